// Round 5
// baseline (197.062 us; speedup 1.0000x reference)
//
#include <hip/hip_runtime.h>

#define NPIX 524288
#define DH 22
#define NHID 11
#define TPB 256
#define TILE (TPB*DH)      // 5632 floats per layer tile
#define TILE4 (TILE/4)     // 1408 float4 slots = 5*256 + 128

__device__ __forceinline__ void activate(float* h) {
#pragma unroll
    for (int j = 15; j < 19; ++j) h[j] = __expf(-h[j]*h[j]) * 2.0f - 1.0f;
    h[21] = __sinf(h[21]);
}

__device__ __forceinline__ void hidden_layer(float* __restrict__ h,
                                             const float* __restrict__ W) {
    float hn[DH];
#pragma unroll
    for (int o = 0; o < DH; ++o) hn[o] = 0.0f;
#pragma unroll
    for (int i = 0; i < DH; ++i) {
        const float hi = h[i];
#pragma unroll
        for (int o = 0; o < DH; ++o)
            hn[o] = fmaf(hi, W[i*DH + o], hn[o]);
    }
    activate(hn);
#pragma unroll
    for (int o = 0; o < DH; ++o) h[o] = hn[o];
}

// unpadded [256][22] tile; 11 ds_write_b64 at word-stride 22 (11 bank-pairs, coprime 16)
__device__ __forceinline__ void write_tile(float* __restrict__ buf,
                                           const float* __restrict__ h, int t) {
    float2* d = (float2*)(buf + t * DH);
#pragma unroll
    for (int k = 0; k < 11; ++k) d[k] = make_float2(h[2*k], h[2*k+1]);
}

// linear ds_read_b128 -> global_store_dwordx4 bursts; tail split is wave-uniform
__device__ __forceinline__ void store_pair(float* __restrict__ g0, float* __restrict__ g1,
                                           const float* __restrict__ lds0,
                                           const float* __restrict__ lds1, int t) {
    const float4* s0 = (const float4*)lds0;
    const float4* s1 = (const float4*)lds1;
#pragma unroll
    for (int k = 0; k < 5; ++k) {
        const int s = t + TPB * k;
        ((float4*)g0)[s] = s0[s];
        ((float4*)g1)[s] = s1[s];
    }
    if (t < 128) { const int s = 1280 + t;       ((float4*)g0)[s] = s0[s]; }
    else         { const int s = 1280 + t - 128; ((float4*)g1)[s] = s1[s]; }
}

__global__ __launch_bounds__(256) void cppn_main(const float* __restrict__ xin,
                                                 const float* __restrict__ Win,
                                                 const float* __restrict__ Whid,
                                                 const float* __restrict__ Wout,
                                                 float* __restrict__ out) {
    __shared__ float lds[2 * TILE];   // 45 KB
    const int t   = threadIdx.x;
    const int blk = blockIdx.x;
    const int p   = blk * TPB + t;

    const float4 xv = ((const float4*)xin)[p];
    ((float4*)(out + (size_t)3 * NPIX))[p] = xv;     // x feature chunk, coalesced

    // ---- layer 0: x[4] @ w_in[4,22] (wave-uniform weights -> s_load) ----
    float h[DH];
#pragma unroll
    for (int o = 0; o < DH; ++o) {
        float a =      xv.x * Win[0*DH + o];
        a = fmaf(xv.y, Win[1*DH + o], a);
        a = fmaf(xv.z, Win[2*DH + o], a);
        a = fmaf(xv.w, Win[3*DH + o], a);
        h[o] = a;
    }
    activate(h);

    float* hbase = out + (size_t)7 * NPIX + (size_t)blk * TILE;
    const size_t chunk = (size_t)NPIX * DH;

    // 12 h-chunks flushed as 6 pairs; stores hide under the next layer's FMAs
    for (int i = 0; i < 6; ++i) {
        __syncthreads();                             // protect LDS vs prior reads
        write_tile(lds, h, t);                       // tile A = h_{2i}
        hidden_layer(h, Whid + (size_t)(2*i) * DH*DH);
        write_tile(lds + TILE, h, t);                // tile B = h_{2i+1}
        __syncthreads();
        store_pair(hbase + (size_t)(2*i) * chunk,
                   hbase + (size_t)(2*i + 1) * chunk, lds, lds + TILE, t);
        if (i < 5) hidden_layer(h, Whid + (size_t)(2*i + 1) * DH*DH);
    }

    // ---- output projection: h11[22] @ w_out[22,3] ----
    float o0 = 0.0f, o1 = 0.0f, o2 = 0.0f;
#pragma unroll
    for (int d = 0; d < DH; ++d) {
        o0 = fmaf(h[d], Wout[d*3 + 0], o0);
        o1 = fmaf(h[d], Wout[d*3 + 1], o1);
        o2 = fmaf(h[d], Wout[d*3 + 2], o2);
    }
    __syncthreads();                                 // last pair's tile reads done
    lds[t*3 + 0] = o0; lds[t*3 + 1] = o1; lds[t*3 + 2] = o2;   // stride 3, coprime 32
    __syncthreads();
    if (t < 192) {                                   // 192 float4 = 768 floats
        const float4 v = ((const float4*)lds)[t];
        ((float4*)(out))[(size_t)blk * 192 + t] = v;                      // first chunk
        ((float4*)(out + (size_t)271 * NPIX))[(size_t)blk * 192 + t] = v; // last chunk
    }
}

extern "C" void kernel_launch(void* const* d_in, const int* in_sizes, int n_in,
                              void* d_out, int out_size, void* d_ws, size_t ws_size,
                              hipStream_t stream) {
    const float* x     = (const float*)d_in[0];
    const float* w_in  = (const float*)d_in[1];
    const float* w_hid = (const float*)d_in[2];
    const float* w_out = (const float*)d_in[3];
    float* o = (float*)d_out;

    cppn_main<<<NPIX / TPB, TPB, 0, stream>>>(x, w_in, w_hid, w_out, o);
}

// Round 7
// 118.365 us; speedup vs baseline: 1.6649x; 1.6649x over previous
//
#include <hip/hip_runtime.h>

#define NPIX 524288
#define DH 22
#define NHID 11
#define TPB 256
#define WTILE (64*DH)     // 1408 floats = per-wave tile (contiguous in global layout)

typedef float f32x4 __attribute__((ext_vector_type(4)));
typedef float f32x2 __attribute__((ext_vector_type(2)));

__device__ __forceinline__ void activate(float* h) {
#pragma unroll
    for (int j = 15; j < 19; ++j) h[j] = __expf(-h[j]*h[j]) * 2.0f - 1.0f;
    h[21] = __sinf(h[21]);
}

__device__ __forceinline__ void hidden_layer(float* __restrict__ h,
                                             const float* __restrict__ W) {
    float hn[DH];
#pragma unroll
    for (int o = 0; o < DH; ++o) hn[o] = 0.0f;
#pragma unroll
    for (int i = 0; i < DH; ++i) {
        const float hi = h[i];
#pragma unroll
        for (int o = 0; o < DH; ++o)
            hn[o] = fmaf(hi, W[i*DH + o], hn[o]);
    }
    activate(hn);
#pragma unroll
    for (int o = 0; o < DH; ++o) h[o] = hn[o];
}

// Wave-private staging: no __syncthreads anywhere. Wave w owns pixels [64w,64w+64)
// whose h-features are CONTIGUOUS (1408 floats) in the global chunk.
// write: 11 ds_write_b64, word-stride 22 (4 words/bank = min aliasing)
// read : linear ds_read_b128 -> nontemporal global_store_dwordx4
__device__ __forceinline__ void flush_h(float* __restrict__ gwave,   // + w*WTILE already
                                        const float* __restrict__ h,
                                        float* __restrict__ wlds, int lane) {
    f32x2* d = (f32x2*)(wlds + lane * DH);
#pragma unroll
    for (int k = 0; k < 11; ++k) { f32x2 v2 = { h[2*k], h[2*k+1] }; d[k] = v2; }
    const f32x4* s4 = (const f32x4*)wlds;   // 352 float4 slots
    f32x4* g4 = (f32x4*)gwave;
#pragma unroll
    for (int k = 0; k < 5; ++k) {
        const int s = lane + 64 * k;
        __builtin_nontemporal_store(s4[s], &g4[s]);
    }
    if (lane < 32) {
        const int s = 320 + lane;
        __builtin_nontemporal_store(s4[s], &g4[s]);
    }
}

__global__ __launch_bounds__(256) void cppn_main(const float* __restrict__ xin,
                                                 const float* __restrict__ Win,
                                                 const float* __restrict__ Whid,
                                                 const float* __restrict__ Wout,
                                                 float* __restrict__ out) {
    __shared__ float lds[4][WTILE];   // 22528 B; per-wave regions
    const int t    = threadIdx.x;
    const int w    = t >> 6;
    const int lane = t & 63;
    const int blk  = blockIdx.x;
    const int p    = blk * TPB + t;
    float* wlds = lds[w];

    const f32x4 xv = ((const f32x4*)xin)[p];
    __builtin_nontemporal_store(xv, &((f32x4*)(out + (size_t)3 * NPIX))[p]);  // x chunk

    // ---- layer 0: x[4] @ w_in[4,22] (wave-uniform weights -> s_load) ----
    float h[DH];
#pragma unroll
    for (int o = 0; o < DH; ++o) {
        float a =      xv.x * Win[0*DH + o];
        a = fmaf(xv.y, Win[1*DH + o], a);
        a = fmaf(xv.z, Win[2*DH + o], a);
        a = fmaf(xv.w, Win[3*DH + o], a);
        h[o] = a;
    }
    activate(h);

    // h-chunk base for this wave
    float* hwave = out + (size_t)7 * NPIX + (size_t)blk * (TPB * DH) + w * WTILE;
    const size_t chunk = (size_t)NPIX * DH;

    flush_h(hwave, h, wlds, lane);
    for (int l = 0; l < NHID; ++l) {
        hidden_layer(h, Whid + (size_t)l * DH * DH);
        flush_h(hwave + (size_t)(l + 1) * chunk, h, wlds, lane);
    }

    // ---- output projection: h11[22] @ w_out[22,3] ----
    float o0 = 0.0f, o1 = 0.0f, o2 = 0.0f;
#pragma unroll
    for (int d = 0; d < DH; ++d) {
        o0 = fmaf(h[d], Wout[d*3 + 0], o0);
        o1 = fmaf(h[d], Wout[d*3 + 1], o1);
        o2 = fmaf(h[d], Wout[d*3 + 2], o2);
    }
    // per-wave stage [64 x 3] (192 floats = 48 float4), store to both out chunks
    wlds[lane*3 + 0] = o0; wlds[lane*3 + 1] = o1; wlds[lane*3 + 2] = o2;
    if (lane < 48) {
        const f32x4 v = ((const f32x4*)wlds)[lane];
        const size_t s = (size_t)blk * 192 + w * 48 + lane;   // float4 index
        __builtin_nontemporal_store(v, &((f32x4*)out)[s]);                        // first chunk
        __builtin_nontemporal_store(v, &((f32x4*)(out + (size_t)271 * NPIX))[s]); // last chunk
    }
}

extern "C" void kernel_launch(void* const* d_in, const int* in_sizes, int n_in,
                              void* d_out, int out_size, void* d_ws, size_t ws_size,
                              hipStream_t stream) {
    const float* x     = (const float*)d_in[0];
    const float* w_in  = (const float*)d_in[1];
    const float* w_hid = (const float*)d_in[2];
    const float* w_out = (const float*)d_in[3];
    float* o = (float*)d_out;

    cppn_main<<<NPIX / TPB, TPB, 0, stream>>>(x, w_in, w_hid, w_out, o);
}